// Round 2
// 518.696 us; speedup vs baseline: 1.0501x; 1.0501x over previous
//
#include <hip/hip_runtime.h>
#include <math.h>

// Problem constants (N,C,H,W = 32,512,64,64; D=4, r=16)
#define N_ 32
#define C_ 512
#define HW_ 4096     // 64*64
#define D_ 4
#define RHID_ 32     // C/r
#define BLOCK_ 128   // C/D
#define C2_ 2048     // C*D

// Native 16-byte vector type (HIP's float4 is a class; the nontemporal
// builtin requires a true scalar/vector type).
typedef float vfloat4 __attribute__((ext_vector_type(4)));

// ---------------- Kernel 1: avg+max pooling over HW per (n,c) ----------------
// One 64-lane wave per plane; 4 planes per 256-thread block. grid = N*C/4.
// 16 float4 loads in flight per thread, pure shuffle reduction (no LDS/barrier).
__global__ __launch_bounds__(256) void pool_kernel(
    const float* __restrict__ x, float* __restrict__ avg_out,
    float* __restrict__ max_out) {
  const int p = (blockIdx.x << 2) + (threadIdx.x >> 6);  // plane id = n*C + c
  const int lane = threadIdx.x & 63;
  const vfloat4* src = (const vfloat4*)(x + (size_t)p * HW_);

  double dsum = 0.0;
  float mx = -INFINITY;
#pragma unroll
  for (int i = 0; i < 16; ++i) {
    vfloat4 v = src[lane + (i << 6)];
    dsum += (double)v.x + (double)v.y + (double)v.z + (double)v.w;
    mx = fmaxf(mx, fmaxf(fmaxf(v.x, v.y), fmaxf(v.z, v.w)));
  }
  // 64-lane wave reduction
#pragma unroll
  for (int off = 32; off > 0; off >>= 1) {
    dsum += __shfl_down(dsum, off);
    mx = fmaxf(mx, __shfl_down(mx, off));
  }
  if (lane == 0) {
    avg_out[p] = (float)(dsum * (1.0 / (double)HW_));
    max_out[p] = mx;
  }
}

// ------------- Kernel 2: shared MLP + per-(n,d) top-128 indices --------------
// grid = N_*D_ = 128 blocks, 256 threads.
// logits[c] for scale d = (relu(avg@W1+b1)+relu(max@W1+b1)) @ W2[:, c*4+d] + 2*b2[c*4+d]
// top_k semantics: descending by value, ties -> smaller index first.
__global__ __launch_bounds__(256) void mlp_topk_kernel(
    const float* __restrict__ avg, const float* __restrict__ mx,
    const float* __restrict__ W1, const float* __restrict__ b1,
    const float* __restrict__ W2, const float* __restrict__ b2,
    int* __restrict__ idx_out) {
  const int n = blockIdx.x >> 2;
  const int d = blockIdx.x & 3;
  const int t = threadIdx.x;

  __shared__ float s_avg[C_];
  __shared__ float s_mx[C_];
  __shared__ double s_pa[8][RHID_];  // partial avg-dots  [group][hidden j]
  __shared__ double s_pm[8][RHID_];  // partial max-dots
  __shared__ double s_h[RHID_];
  __shared__ unsigned long long s_key[C_];

  // stage pooled vectors for sample n (coalesced)
#pragma unroll
  for (int i = 0; i < 2; ++i) {
    int c = t + i * 256;
    s_avg[c] = avg[n * C_ + c];
    s_mx[c] = mx[n * C_ + c];
  }
  __syncthreads();

  // hidden layer (fp64), parallel over all 256 threads:
  // thread t -> hidden unit j = t&31, channel chunk g = t>>5 (64 channels).
  // W1 loads: lanes j=0..31 read 128 consecutive bytes -> coalesced.
  {
    const int j = t & 31;
    const int g = t >> 5;
    double pa = 0.0, pm = 0.0;
#pragma unroll 4
    for (int i = 0; i < 64; ++i) {
      const int c = (g << 6) + i;
      const double w = (double)W1[c * RHID_ + j];
      pa += (double)s_avg[c] * w;
      pm += (double)s_mx[c] * w;
    }
    s_pa[g][j] = pa;
    s_pm[g][j] = pm;
  }
  __syncthreads();
  if (t < RHID_) {
    double a = (double)b1[t];
    double m = a;
#pragma unroll
    for (int g = 0; g < 8; ++g) {
      a += s_pa[g][t];
      m += s_pm[g][t];
    }
    s_h[t] = (a > 0.0 ? a : 0.0) + (m > 0.0 ? m : 0.0);
  }
  __syncthreads();

  // logits for this scale d, packed into descending-sortable keys
  for (int c = t; c < C_; c += 256) {
    const int col = c * D_ + d;
    double acc = 2.0 * (double)b2[col];
#pragma unroll
    for (int j = 0; j < RHID_; ++j)
      acc += s_h[j] * (double)W2[j * C2_ + col];
    float f = (float)acc;
    unsigned u = __float_as_uint(f);
    u = (u & 0x80000000u) ? ~u : (u | 0x80000000u);  // order-preserving map
    // secondary key: 511-c so that descending key sort -> ascending index on ties
    s_key[c] = ((unsigned long long)u << 32) | (unsigned)(C_ - 1 - c);
  }
  __syncthreads();

  // bitonic sort, 512 elems, descending
  for (int kk = 2; kk <= C_; kk <<= 1) {
    for (int jj = kk >> 1; jj > 0; jj >>= 1) {
#pragma unroll
      for (int r = 0; r < 2; ++r) {
        int i = t + r * 256;
        int ixj = i ^ jj;
        if (ixj > i) {
          bool ddd = ((i & kk) != 0);  // descending overall
          unsigned long long a = s_key[i], b = s_key[ixj];
          if ((a > b) == ddd) { s_key[i] = b; s_key[ixj] = a; }
        }
      }
      __syncthreads();
    }
  }

  if (t < BLOCK_) {
    int c = (C_ - 1) - (int)(s_key[t] & 0xFFFFFFFFu);
    idx_out[(n * D_ + d) * BLOCK_ + t] = c;
  }
}

// ---------------- Kernel 3: gather channels per selected index ---------------
// One wave per output plane; 4 planes per block, grid = N*C/4.
// Non-temporal stores keep x resident in Infinity Cache so the scattered
// channel reads hit L3 (x = 256 MiB = exactly L3 size, just streamed by pool).
__global__ __launch_bounds__(256) void gather_kernel(
    const float* __restrict__ x, const int* __restrict__ idx,
    float* __restrict__ out) {
  const int p = (blockIdx.x << 2) + (threadIdx.x >> 6);  // output plane n*C + j
  const int lane = threadIdx.x & 63;
  const int n = p >> 9;
  const int c = idx[p];
  const vfloat4* src = (const vfloat4*)(x + ((size_t)(n * C_ + c)) * HW_);
  vfloat4* dst = (vfloat4*)(out + (size_t)p * HW_);
#pragma unroll
  for (int i = 0; i < 16; ++i) {
    vfloat4 v = src[lane + (i << 6)];
    __builtin_nontemporal_store(v, &dst[lane + (i << 6)]);
  }
}

extern "C" void kernel_launch(void* const* d_in, const int* in_sizes, int n_in,
                              void* d_out, int out_size, void* d_ws, size_t ws_size,
                              hipStream_t stream) {
  const float* x  = (const float*)d_in[0];
  const float* W1 = (const float*)d_in[1];
  const float* b1 = (const float*)d_in[2];
  const float* W2 = (const float*)d_in[3];
  const float* b2 = (const float*)d_in[4];
  float* out = (float*)d_out;

  // workspace layout: avg[N*C] f32 | max[N*C] f32 | idx[N*C] i32  (192 KB)
  float* ws_avg = (float*)d_ws;
  float* ws_max = ws_avg + N_ * C_;
  int* ws_idx = (int*)(ws_max + N_ * C_);

  pool_kernel<<<(N_ * C_) / 4, 256, 0, stream>>>(x, ws_avg, ws_max);
  mlp_topk_kernel<<<N_ * D_, 256, 0, stream>>>(ws_avg, ws_max, W1, b1, W2, b2,
                                               ws_idx);
  gather_kernel<<<(N_ * C_) / 4, 256, 0, stream>>>(x, ws_idx, out);
}